// Round 4
// baseline (1022.214 us; speedup 1.0000x reference)
//
#include <hip/hip_runtime.h>
#include <hip/hip_fp16.h>

// RzLinear: C[N,M] = A[N,K] * W[K,M],  W[k,m] = hw[gidx[k*M+m]]
// Round 4 (= round 3 resubmitted; infra timeout, never measured):
//  - prep: LDS-free, per-thread granule production, coalesced 16B writes,
//    chunk-start gidx reads (wave-broadcast) + contiguous hw reads.
//  - gemm: depth-1 2-phase pipeline (prefetch W via global_load_lds dbuf +
//    A via regs before MFMA of current tile), T14 write-late A staging,
//    setprio around MFMA cluster. Numerics identical to round 2
//    (3-term split-f16: Ah*Wh + Ah*Wl + Al*Wh).

#define N_TOK 8192
#define KDIM  4096
#define MDIM  4096

#define BM 128
#define BN 128
#define BK 32

#define PLANE_BYTES (33554432ull)     // f16 plane 4096*4096*2
#define WS_NEEDED   (67108864ull)     // two planes

typedef _Float16 f16x8 __attribute__((ext_vector_type(8)));
typedef _Float16 f16x4 __attribute__((ext_vector_type(4)));
typedef float    f32x4 __attribute__((ext_vector_type(4)));

__device__ __forceinline__ void gload16(const void* g, void* l) {
    __builtin_amdgcn_global_load_lds(
        (const __attribute__((address_space(1))) unsigned int*)g,
        (__attribute__((address_space(3))) unsigned int*)l, 16, 0, 0);
}

// ---------------- kernel 1: W materialization (LDS-free) ----------------
// Tile ti = mt*128 + kt (128 m-rows x 32 k). Output = 512 granules of 16B,
// phys granule p holds logical (r = p>>2, q_log = (p&3) ^ ((r>>1)&3)):
// 8 k-consecutive f16 of m-row r. Pre-swizzled for the GEMM's ds_reads.
__global__ __launch_bounds__(256)
void rz_prep_w2(const float* __restrict__ hw, const int* __restrict__ gidx,
                _Float16* __restrict__ wh, _Float16* __restrict__ wl) {
    const int t  = threadIdx.x;
    const int ti = blockIdx.x;          // 0..4095
    const int mt = ti >> 7;
    const int kt = ti & 127;
    _Float16* whT = wh + (size_t)ti * 4096;
    _Float16* wlT = wl + (size_t)ti * 4096;

    #pragma unroll
    for (int pass = 0; pass < 2; ++pass) {
        const int p = t + pass * 256;            // 0..511
        const int r = p >> 2;                    // m-local 0..127
        const int qlog = (p & 3) ^ ((r >> 1) & 3);
        const int mglob = mt * 128 + r;
        const int mcb = mglob & ~31;             // chunk-aligned m
        const int mo  = mglob & 31;

        int starts[8];
        #pragma unroll
        for (int j = 0; j < 8; ++j) {
            const int kglob = kt * 32 + qlog * 8 + j;
            starts[j] = gidx[(size_t)kglob * MDIM + mcb];  // broadcast in wave
        }
        f16x8 hv, lv;
        #pragma unroll
        for (int j = 0; j < 8; ++j) {
            const float v = hw[starts[j] + mo];  // contiguous per chunk
            const _Float16 h = (_Float16)v;
            hv[j] = h;
            lv[j] = (_Float16)(v - (float)h);
        }
        *reinterpret_cast<f16x8*>(&whT[p * 8]) = hv;  // coalesced 16B/lane
        *reinterpret_cast<f16x8*>(&wlT[p * 8]) = lv;
    }
}

// ---------------- kernel 2: split-f16 GEMM, depth-1 pipeline ----------------
__global__ __launch_bounds__(256, 2)
void rz_gemm2(const float* __restrict__ x,
              const _Float16* __restrict__ wh, const _Float16* __restrict__ wl,
              float* __restrict__ out) {
    __shared__ __align__(16) _Float16 Ah[4096];
    __shared__ __align__(16) _Float16 Al[4096];
    __shared__ __align__(16) _Float16 Bh[2][4096];
    __shared__ __align__(16) _Float16 Bl[2][4096];

    const int tid  = threadIdx.x;
    const int lane = tid & 63;
    const int wave = tid >> 6;
    const int wr   = wave >> 1;
    const int wc   = wave & 1;

    const int bid = blockIdx.x;
    const int swz = (bid & 7) * 256 + (bid >> 3);   // bijective: 2048 % 8 == 0
    const int n0  = (swz >> 5) * BM;
    const int mt  = (swz & 31);
    const int m0  = mt * BN;

    const int l15  = lane & 15;
    const int qsel = lane >> 4;

    int a_off[4], b_off[4];
    #pragma unroll
    for (int mi = 0; mi < 4; ++mi) {
        const int rr = wr * 64 + mi * 16 + l15;
        a_off[mi] = rr * 32 + ((qsel ^ ((rr >> 1) & 3)) * 8);
    }
    #pragma unroll
    for (int ni = 0; ni < 4; ++ni) {
        const int cc = wc * 64 + ni * 16 + l15;
        b_off[ni] = cc * 32 + ((qsel ^ ((cc >> 1) & 3)) * 8);
    }

    const int ar0 = tid >> 2;     // A staging row
    const int aq0 = tid & 3;      // A staging k-granule

    f32x4 acc[4][4];
    #pragma unroll
    for (int i = 0; i < 4; ++i)
        #pragma unroll
        for (int j = 0; j < 4; ++j)
            acc[i][j] = (f32x4)0.0f;

    float4 av[2][2];              // A prefetch registers (16 floats)

    #define LOAD_A(KT) do {                                                   \
        _Pragma("unroll")                                                     \
        for (int pp = 0; pp < 2; ++pp) {                                      \
            const int r = ar0 + pp * 64;                                      \
            const float* src = &x[(size_t)(n0 + r) * KDIM + (KT) * BK + aq0 * 8]; \
            av[pp][0] = *reinterpret_cast<const float4*>(src);                \
            av[pp][1] = *reinterpret_cast<const float4*>(src + 4);            \
        } } while (0)

    #define WRITE_A() do {                                                    \
        _Pragma("unroll")                                                     \
        for (int pp = 0; pp < 2; ++pp) {                                      \
            const int r = ar0 + pp * 64;                                      \
            const float s[8] = {av[pp][0].x, av[pp][0].y, av[pp][0].z, av[pp][0].w, \
                                av[pp][1].x, av[pp][1].y, av[pp][1].z, av[pp][1].w}; \
            f16x8 hv, lv;                                                     \
            _Pragma("unroll")                                                 \
            for (int j = 0; j < 8; ++j) {                                     \
                const _Float16 h = (_Float16)s[j];                            \
                hv[j] = h;                                                    \
                lv[j] = (_Float16)(s[j] - (float)h);                          \
            }                                                                 \
            const int phys = r * 32 + ((aq0 ^ ((r >> 1) & 3)) * 8);           \
            *reinterpret_cast<f16x8*>(&Ah[phys]) = hv;                        \
            *reinterpret_cast<f16x8*>(&Al[phys]) = lv;                        \
        } } while (0)

    #define STAGE_W(KT, BUF) do {                                             \
        const _Float16* whT = wh + ((size_t)(mt * 128 + (KT))) * 4096;        \
        const _Float16* wlT = wl + ((size_t)(mt * 128 + (KT))) * 4096;        \
        gload16(whT + tid * 8,        &Bh[BUF][tid * 8]);                     \
        gload16(whT + 2048 + tid * 8, &Bh[BUF][2048 + tid * 8]);              \
        gload16(wlT + tid * 8,        &Bl[BUF][tid * 8]);                     \
        gload16(wlT + 2048 + tid * 8, &Bl[BUF][2048 + tid * 8]);              \
    } while (0)

    // ---- prologue: stage tile 0 ----
    LOAD_A(0);
    STAGE_W(0, 0);
    WRITE_A();
    __syncthreads();   // drains vmcnt (gload_lds) + lgkmcnt (ds_write)

    for (int t = 0; t < 128; ++t) {
        const int cur = t & 1;
        if (t < 127) {           // issue next tile's loads BEFORE compute
            LOAD_A(t + 1);
            STAGE_W(t + 1, cur ^ 1);
        }

        // fragment reads of current tile
        f16x8 fah[4], fal[4], fbh[4], fbl[4];
        #pragma unroll
        for (int mi = 0; mi < 4; ++mi) {
            fah[mi] = *reinterpret_cast<const f16x8*>(&Ah[a_off[mi]]);
            fal[mi] = *reinterpret_cast<const f16x8*>(&Al[a_off[mi]]);
        }
        #pragma unroll
        for (int ni = 0; ni < 4; ++ni) {
            fbh[ni] = *reinterpret_cast<const f16x8*>(&Bh[cur][b_off[ni]]);
            fbl[ni] = *reinterpret_cast<const f16x8*>(&Bl[cur][b_off[ni]]);
        }
        asm volatile("s_waitcnt lgkmcnt(0)" ::: "memory");
        __builtin_amdgcn_sched_barrier(0);     // rule #18
        __builtin_amdgcn_s_barrier();          // all frag reads done -> Ah/Al free

        __builtin_amdgcn_s_setprio(1);
        #pragma unroll
        for (int mi = 0; mi < 4; ++mi)
            #pragma unroll
            for (int ni = 0; ni < 4; ++ni)
                acc[mi][ni] = __builtin_amdgcn_mfma_f32_16x16x32_f16(fah[mi], fbh[ni], acc[mi][ni], 0, 0, 0);
        #pragma unroll
        for (int mi = 0; mi < 4; ++mi)
            #pragma unroll
            for (int ni = 0; ni < 4; ++ni)
                acc[mi][ni] = __builtin_amdgcn_mfma_f32_16x16x32_f16(fah[mi], fbl[ni], acc[mi][ni], 0, 0, 0);
        #pragma unroll
        for (int mi = 0; mi < 4; ++mi)
            #pragma unroll
            for (int ni = 0; ni < 4; ++ni)
                acc[mi][ni] = __builtin_amdgcn_mfma_f32_16x16x32_f16(fal[mi], fbh[ni], acc[mi][ni], 0, 0, 0);
        __builtin_amdgcn_s_setprio(0);

        if (t < 127) WRITE_A();   // convert + ds_write next A (vmcnt waited by compiler)
        __syncthreads();          // drains vmcnt(0) lgkmcnt(0): W(t+1) + A writes ready
    }

    // ---- epilogue: C/D layout col=lane&15, row=(lane>>4)*4+r ----
    #pragma unroll
    for (int mi = 0; mi < 4; ++mi) {
        const int row = n0 + wr * 64 + mi * 16 + (lane >> 4) * 4;
        #pragma unroll
        for (int ni = 0; ni < 4; ++ni) {
            const int col = m0 + wc * 64 + ni * 16 + l15;
            #pragma unroll
            for (int r = 0; r < 4; ++r)
                out[(size_t)(row + r) * MDIM + col] = acc[mi][ni][r];
        }
    }
    #undef LOAD_A
    #undef WRITE_A
    #undef STAGE_W
}

// ---------------- fallback (round-1 kernel, known-correct) ----------------
#define LDT 40
__global__ __launch_bounds__(256, 2)
void rz_linear_splitf16_fb(const float* __restrict__ hw,
                           const float* __restrict__ x,
                           const int*   __restrict__ gidx,
                           float*       __restrict__ out) {
    __shared__ __align__(16) _Float16 Ah[BM][LDT];
    __shared__ __align__(16) _Float16 Al[BM][LDT];
    __shared__ __align__(16) _Float16 Wh[BN][LDT];
    __shared__ __align__(16) _Float16 Wl[BN][LDT];
    const int tid  = threadIdx.x;
    const int lane = tid & 63;
    const int wave = tid >> 6;
    const int wr   = wave >> 1;
    const int wc   = wave & 1;
    const int bid = blockIdx.x;
    const int swz = (bid & 7) * 256 + (bid >> 3);
    const int n0  = (swz >> 5) * BM;
    const int m0  = (swz & 31) * BN;
    const int a_row = tid >> 3;
    const int a_kc  = tid & 7;
    const int w_m   = tid & 127;
    const int w_kg  = tid >> 7;
    const int l15  = lane & 15;
    const int koff = (lane >> 4) * 8;
    f32x4 acc[4][4];
    #pragma unroll
    for (int i = 0; i < 4; ++i)
        #pragma unroll
        for (int j = 0; j < 4; ++j) acc[i][j] = (f32x4)0.0f;
    for (int k0 = 0; k0 < KDIM; k0 += BK) {
        #pragma unroll
        for (int p = 0; p < 4; ++p) {
            const int n = a_row + p * 32;
            const float4 v = *reinterpret_cast<const float4*>(
                &x[(size_t)(n0 + n) * KDIM + k0 + a_kc * 4]);
            const _Float16 h0 = (_Float16)v.x, h1 = (_Float16)v.y,
                           h2 = (_Float16)v.z, h3 = (_Float16)v.w;
            f16x4 hv = {h0, h1, h2, h3};
            f16x4 lv = {(_Float16)(v.x - (float)h0), (_Float16)(v.y - (float)h1),
                        (_Float16)(v.z - (float)h2), (_Float16)(v.w - (float)h3)};
            *reinterpret_cast<f16x4*>(&Ah[n][a_kc * 4]) = hv;
            *reinterpret_cast<f16x4*>(&Al[n][a_kc * 4]) = lv;
        }
        #pragma unroll
        for (int q = 0; q < 2; ++q) {
            const int kb = (w_kg + 2 * q) * 8;
            float wv[8];
            #pragma unroll
            for (int j = 0; j < 8; ++j) {
                const int k = k0 + kb + j;
                wv[j] = hw[gidx[k * MDIM + m0 + w_m]];
            }
            f16x8 hv, lv;
            #pragma unroll
            for (int j = 0; j < 8; ++j) {
                const _Float16 h = (_Float16)wv[j];
                hv[j] = h;
                lv[j] = (_Float16)(wv[j] - (float)h);
            }
            *reinterpret_cast<f16x8*>(&Wh[w_m][kb]) = hv;
            *reinterpret_cast<f16x8*>(&Wl[w_m][kb]) = lv;
        }
        __syncthreads();
        f16x8 ah[4], al[4], bh[4], bl[4];
        #pragma unroll
        for (int mi = 0; mi < 4; ++mi) {
            const int r = wr * 64 + mi * 16 + l15;
            ah[mi] = *reinterpret_cast<const f16x8*>(&Ah[r][koff]);
            al[mi] = *reinterpret_cast<const f16x8*>(&Al[r][koff]);
        }
        #pragma unroll
        for (int ni = 0; ni < 4; ++ni) {
            const int c = wc * 64 + ni * 16 + l15;
            bh[ni] = *reinterpret_cast<const f16x8*>(&Wh[c][koff]);
            bl[ni] = *reinterpret_cast<const f16x8*>(&Wl[c][koff]);
        }
        #pragma unroll
        for (int mi = 0; mi < 4; ++mi)
            #pragma unroll
            for (int ni = 0; ni < 4; ++ni) {
                acc[mi][ni] = __builtin_amdgcn_mfma_f32_16x16x32_f16(ah[mi], bh[ni], acc[mi][ni], 0, 0, 0);
                acc[mi][ni] = __builtin_amdgcn_mfma_f32_16x16x32_f16(ah[mi], bl[ni], acc[mi][ni], 0, 0, 0);
                acc[mi][ni] = __builtin_amdgcn_mfma_f32_16x16x32_f16(al[mi], bh[ni], acc[mi][ni], 0, 0, 0);
            }
        __syncthreads();
    }
    #pragma unroll
    for (int mi = 0; mi < 4; ++mi) {
        const int row = n0 + wr * 64 + mi * 16 + (lane >> 4) * 4;
        #pragma unroll
        for (int ni = 0; ni < 4; ++ni) {
            const int col = m0 + wc * 64 + ni * 16 + l15;
            #pragma unroll
            for (int r = 0; r < 4; ++r)
                out[(size_t)(row + r) * MDIM + col] = acc[mi][ni][r];
        }
    }
}

extern "C" void kernel_launch(void* const* d_in, const int* in_sizes, int n_in,
                              void* d_out, int out_size, void* d_ws, size_t ws_size,
                              hipStream_t stream) {
    const float* hw   = (const float*)d_in[0];
    const float* x    = (const float*)d_in[1];
    const int*   gidx = (const int*)  d_in[2];
    float* out = (float*)d_out;

    if (ws_size >= WS_NEEDED) {
        _Float16* whp = (_Float16*)d_ws;
        _Float16* wlp = (_Float16*)((char*)d_ws + PLANE_BYTES);
        rz_prep_w2<<<4096, 256, 0, stream>>>(hw, gidx, whp, wlp);
        rz_gemm2<<<2048, 256, 0, stream>>>(x, whp, wlp, out);
    } else {
        rz_linear_splitf16_fb<<<2048, 256, 0, stream>>>(hw, x, gidx, out);
    }
}

// Round 5
// 912.396 us; speedup vs baseline: 1.1204x; 1.1204x over previous
//
#include <hip/hip_runtime.h>
#include <hip/hip_fp16.h>

// RzLinear: C[N,M] = A[N,K] * W[K,M],  W[k,m] = hw[gidx[k*M+m]]
// Round 5:
//  - revert round-4 pipeline (regressed: occupancy loss > prefetch gain).
//  - GEMM: round-2 2-barrier structure, but wave tile 128x64 (block 256x128,
//    grid 1024): -25% LDS bytes/FLOP, -50% W global re-reads.
//  - prep: thread->granule remap so gidx gathers touch ~4 lines/instr.
//  Numerics identical (3-term split-f16: Ah*Wh + Ah*Wl + Al*Wh, same order).

#define N_TOK 8192
#define KDIM  4096
#define MDIM  4096

#define PLANE_BYTES (33554432ull)     // f16 plane 4096*4096*2
#define WS_NEEDED   (67108864ull)     // two planes

typedef _Float16 f16x8 __attribute__((ext_vector_type(8)));
typedef _Float16 f16x4 __attribute__((ext_vector_type(4)));
typedef float    f32x4 __attribute__((ext_vector_type(4)));

__device__ __forceinline__ void gload16(const void* g, void* l) {
    __builtin_amdgcn_global_load_lds(
        (const __attribute__((address_space(1))) unsigned int*)g,
        (__attribute__((address_space(3))) unsigned int*)l, 16, 0, 0);
}

// ---------------- kernel 1: W materialization (LDS-free) ----------------
// Tile ti = mt*128 + kt. Output granule p = r*4 + qphys (16B, 8 k-elems of
// m-row r), qphys = qlog ^ ((r>>1)&3)  [pre-swizzled for GEMM ds_reads].
// Thread map: r = (t>>2)+pass*64, qlog = t&3  -> per gidx gather only 4
// distinct kglob lines per instr; hw reads span 4 chunks (contiguous within).
__global__ __launch_bounds__(256)
void rz_prep_w3(const float* __restrict__ hw, const int* __restrict__ gidx,
                _Float16* __restrict__ wh, _Float16* __restrict__ wl) {
    const int t  = threadIdx.x;
    const int ti = blockIdx.x;          // 0..4095
    const int mt = ti >> 7;
    const int kt = ti & 127;
    _Float16* whT = wh + (size_t)ti * 4096;
    _Float16* wlT = wl + (size_t)ti * 4096;

    #pragma unroll
    for (int pass = 0; pass < 2; ++pass) {
        const int r    = (t >> 2) + pass * 64;   // m-local 0..127
        const int qlog = t & 3;
        const int p    = r * 4 + (qlog ^ ((r >> 1) & 3));
        const int mglob = mt * 128 + r;
        const int mcb  = mglob & ~31;            // chunk-aligned m (wave-uniform)
        const int mo   = mglob & 31;

        int starts[8];
        #pragma unroll
        for (int j = 0; j < 8; ++j) {
            const int kglob = kt * 32 + qlog * 8 + j;
            starts[j] = gidx[(size_t)kglob * MDIM + mcb];  // 4 lines/instr
        }
        f16x8 hv, lv;
        #pragma unroll
        for (int j = 0; j < 8; ++j) {
            const float v = hw[starts[j] + mo];  // contiguous per chunk
            const _Float16 h = (_Float16)v;
            hv[j] = h;
            lv[j] = (_Float16)(v - (float)h);
        }
        *reinterpret_cast<f16x8*>(&whT[p * 8]) = hv;
        *reinterpret_cast<f16x8*>(&wlT[p * 8]) = lv;
    }
}

// ---------------- kernel 2: split-f16 GEMM, 256x128 block ----------------
// 4 waves 2x2; wave tile 128(n) x 64(m) = 8x4 16x16x32 frags, acc 128 VGPR.
__global__ __launch_bounds__(256, 2)
void rz_gemm3(const float* __restrict__ x,
              const _Float16* __restrict__ wh, const _Float16* __restrict__ wl,
              float* __restrict__ out) {
    __shared__ __align__(16) _Float16 Ah[8192];   // 256 rows x 32 k
    __shared__ __align__(16) _Float16 Al[8192];
    __shared__ __align__(16) _Float16 Bh[4096];   // 128 cols x 32 k
    __shared__ __align__(16) _Float16 Bl[4096];

    const int tid  = threadIdx.x;
    const int lane = tid & 63;
    const int wave = tid >> 6;
    const int wr   = wave >> 1;       // n-half (0..1): rows wr*128..
    const int wc   = wave & 1;        // m-half (0..1): cols wc*64..

    const int bid = blockIdx.x;
    const int swz = (bid & 7) * 128 + (bid >> 3);   // bijective: 1024 % 8 == 0
    const int n0  = (swz >> 5) * 256;               // 32 n-blocks
    const int mt  = (swz & 31);                     // 32 m-tiles
    const int m0  = mt * 128;

    const int l15  = lane & 15;
    const int qsel = lane >> 4;

    int a_off[8], b_off[4];
    #pragma unroll
    for (int mi = 0; mi < 8; ++mi) {
        const int rr = wr * 128 + mi * 16 + l15;
        a_off[mi] = rr * 32 + ((qsel ^ ((rr >> 1) & 3)) * 8);
    }
    #pragma unroll
    for (int ni = 0; ni < 4; ++ni) {
        const int cc = wc * 64 + ni * 16 + l15;
        b_off[ni] = cc * 32 + ((qsel ^ ((cc >> 1) & 3)) * 8);
    }

    const int ar0 = tid >> 2;     // A staging row base (0..63, +64/pass)
    const int aq0 = tid & 3;      // A staging k-granule

    f32x4 acc[8][4];
    #pragma unroll
    for (int i = 0; i < 8; ++i)
        #pragma unroll
        for (int j = 0; j < 4; ++j)
            acc[i][j] = (f32x4)0.0f;

    for (int kt = 0; kt < KDIM / 32; ++kt) {
        // ---- W: 4x global_load_lds dwordx4 (pre-swizzled src, linear dest) ----
        const _Float16* whT = wh + ((size_t)(mt * 128 + kt)) * 4096;
        const _Float16* wlT = wl + ((size_t)(mt * 128 + kt)) * 4096;
        gload16(whT + tid * 8,        &Bh[tid * 8]);
        gload16(whT + 2048 + tid * 8, &Bh[2048 + tid * 8]);
        gload16(wlT + tid * 8,        &Bl[tid * 8]);
        gload16(wlT + 2048 + tid * 8, &Bl[2048 + tid * 8]);

        // ---- A: reg-stage fp32 -> f16 hi/lo, swizzled ds_write (4 passes) ----
        #pragma unroll
        for (int pass = 0; pass < 4; ++pass) {
            const int r = ar0 + pass * 64;
            const float* src = &x[(size_t)(n0 + r) * KDIM + kt * 32 + aq0 * 8];
            const float4 v0 = *reinterpret_cast<const float4*>(src);
            const float4 v1 = *reinterpret_cast<const float4*>(src + 4);
            const float s[8] = {v0.x, v0.y, v0.z, v0.w, v1.x, v1.y, v1.z, v1.w};
            f16x8 hv, lv;
            #pragma unroll
            for (int j = 0; j < 8; ++j) {
                const _Float16 h = (_Float16)s[j];
                hv[j] = h;
                lv[j] = (_Float16)(s[j] - (float)h);
            }
            const int phys = r * 32 + ((aq0 ^ ((r >> 1) & 3)) * 8);
            *reinterpret_cast<f16x8*>(&Ah[phys]) = hv;
            *reinterpret_cast<f16x8*>(&Al[phys]) = lv;
        }
        __syncthreads();   // drains vmcnt (gload_lds) + lgkmcnt (ds_write)

        // ---- fragments + 96 MFMA ----
        f16x8 fbh[4], fbl[4];
        #pragma unroll
        for (int ni = 0; ni < 4; ++ni) {
            fbh[ni] = *reinterpret_cast<const f16x8*>(&Bh[b_off[ni]]);
            fbl[ni] = *reinterpret_cast<const f16x8*>(&Bl[b_off[ni]]);
        }
        #pragma unroll
        for (int mi = 0; mi < 8; ++mi) {
            const f16x8 fah = *reinterpret_cast<const f16x8*>(&Ah[a_off[mi]]);
            const f16x8 fal = *reinterpret_cast<const f16x8*>(&Al[a_off[mi]]);
            #pragma unroll
            for (int ni = 0; ni < 4; ++ni) {
                acc[mi][ni] = __builtin_amdgcn_mfma_f32_16x16x32_f16(fah, fbh[ni], acc[mi][ni], 0, 0, 0);
                acc[mi][ni] = __builtin_amdgcn_mfma_f32_16x16x32_f16(fah, fbl[ni], acc[mi][ni], 0, 0, 0);
                acc[mi][ni] = __builtin_amdgcn_mfma_f32_16x16x32_f16(fal, fbh[ni], acc[mi][ni], 0, 0, 0);
            }
        }
        __syncthreads();
    }

    // ---- epilogue: C/D layout col=lane&15, row=(lane>>4)*4+r ----
    #pragma unroll
    for (int mi = 0; mi < 8; ++mi) {
        const int row = n0 + wr * 128 + mi * 16 + (lane >> 4) * 4;
        #pragma unroll
        for (int ni = 0; ni < 4; ++ni) {
            const int col = m0 + wc * 64 + ni * 16 + l15;
            #pragma unroll
            for (int r = 0; r < 4; ++r)
                out[(size_t)(row + r) * MDIM + col] = acc[mi][ni][r];
        }
    }
}

// ---------------- fallback (round-1 kernel, known-correct) ----------------
#define BM 128
#define BN 128
#define LDT 40
__global__ __launch_bounds__(256, 2)
void rz_linear_splitf16_fb(const float* __restrict__ hw,
                           const float* __restrict__ x,
                           const int*   __restrict__ gidx,
                           float*       __restrict__ out) {
    __shared__ __align__(16) _Float16 Ah[BM][LDT];
    __shared__ __align__(16) _Float16 Al[BM][LDT];
    __shared__ __align__(16) _Float16 Wh[BN][LDT];
    __shared__ __align__(16) _Float16 Wl[BN][LDT];
    const int tid  = threadIdx.x;
    const int lane = tid & 63;
    const int wave = tid >> 6;
    const int wr   = wave >> 1;
    const int wc   = wave & 1;
    const int bid = blockIdx.x;
    const int swz = (bid & 7) * 256 + (bid >> 3);
    const int n0  = (swz >> 5) * BM;
    const int m0  = (swz & 31) * BN;
    const int a_row = tid >> 3;
    const int a_kc  = tid & 7;
    const int w_m   = tid & 127;
    const int w_kg  = tid >> 7;
    const int l15  = lane & 15;
    const int koff = (lane >> 4) * 8;
    f32x4 acc[4][4];
    #pragma unroll
    for (int i = 0; i < 4; ++i)
        #pragma unroll
        for (int j = 0; j < 4; ++j) acc[i][j] = (f32x4)0.0f;
    for (int k0 = 0; k0 < KDIM; k0 += 32) {
        #pragma unroll
        for (int p = 0; p < 4; ++p) {
            const int n = a_row + p * 32;
            const float4 v = *reinterpret_cast<const float4*>(
                &x[(size_t)(n0 + n) * KDIM + k0 + a_kc * 4]);
            const _Float16 h0 = (_Float16)v.x, h1 = (_Float16)v.y,
                           h2 = (_Float16)v.z, h3 = (_Float16)v.w;
            f16x4 hv = {h0, h1, h2, h3};
            f16x4 lv = {(_Float16)(v.x - (float)h0), (_Float16)(v.y - (float)h1),
                        (_Float16)(v.z - (float)h2), (_Float16)(v.w - (float)h3)};
            *reinterpret_cast<f16x4*>(&Ah[n][a_kc * 4]) = hv;
            *reinterpret_cast<f16x4*>(&Al[n][a_kc * 4]) = lv;
        }
        #pragma unroll
        for (int q = 0; q < 2; ++q) {
            const int kb = (w_kg + 2 * q) * 8;
            float wv[8];
            #pragma unroll
            for (int j = 0; j < 8; ++j) {
                const int k = k0 + kb + j;
                wv[j] = hw[gidx[k * MDIM + m0 + w_m]];
            }
            f16x8 hv, lv;
            #pragma unroll
            for (int j = 0; j < 8; ++j) {
                const _Float16 h = (_Float16)wv[j];
                hv[j] = h;
                lv[j] = (_Float16)(wv[j] - (float)h);
            }
            *reinterpret_cast<f16x8*>(&Wh[w_m][kb]) = hv;
            *reinterpret_cast<f16x8*>(&Wl[w_m][kb]) = lv;
        }
        __syncthreads();
        f16x8 ah[4], al[4], bh[4], bl[4];
        #pragma unroll
        for (int mi = 0; mi < 4; ++mi) {
            const int r = wr * 64 + mi * 16 + l15;
            ah[mi] = *reinterpret_cast<const f16x8*>(&Ah[r][koff]);
            al[mi] = *reinterpret_cast<const f16x8*>(&Al[r][koff]);
        }
        #pragma unroll
        for (int ni = 0; ni < 4; ++ni) {
            const int c = wc * 64 + ni * 16 + l15;
            bh[ni] = *reinterpret_cast<const f16x8*>(&Wh[c][koff]);
            bl[ni] = *reinterpret_cast<const f16x8*>(&Wl[c][koff]);
        }
        #pragma unroll
        for (int mi = 0; mi < 4; ++mi)
            #pragma unroll
            for (int ni = 0; ni < 4; ++ni) {
                acc[mi][ni] = __builtin_amdgcn_mfma_f32_16x16x32_f16(ah[mi], bh[ni], acc[mi][ni], 0, 0, 0);
                acc[mi][ni] = __builtin_amdgcn_mfma_f32_16x16x32_f16(ah[mi], bl[ni], acc[mi][ni], 0, 0, 0);
                acc[mi][ni] = __builtin_amdgcn_mfma_f32_16x16x32_f16(al[mi], bh[ni], acc[mi][ni], 0, 0, 0);
            }
        __syncthreads();
    }
    #pragma unroll
    for (int mi = 0; mi < 4; ++mi) {
        const int row = n0 + wr * 64 + mi * 16 + (lane >> 4) * 4;
        #pragma unroll
        for (int ni = 0; ni < 4; ++ni) {
            const int col = m0 + wc * 64 + ni * 16 + l15;
            #pragma unroll
            for (int r = 0; r < 4; ++r)
                out[(size_t)(row + r) * MDIM + col] = acc[mi][ni][r];
        }
    }
}

extern "C" void kernel_launch(void* const* d_in, const int* in_sizes, int n_in,
                              void* d_out, int out_size, void* d_ws, size_t ws_size,
                              hipStream_t stream) {
    const float* hw   = (const float*)d_in[0];
    const float* x    = (const float*)d_in[1];
    const int*   gidx = (const int*)  d_in[2];
    float* out = (float*)d_out;

    if (ws_size >= WS_NEEDED) {
        _Float16* whp = (_Float16*)d_ws;
        _Float16* wlp = (_Float16*)((char*)d_ws + PLANE_BYTES);
        rz_prep_w3<<<4096, 256, 0, stream>>>(hw, gidx, whp, wlp);
        rz_gemm3<<<1024, 256, 0, stream>>>(x, whp, wlp, out);
    } else {
        rz_linear_splitf16_fb<<<2048, 256, 0, stream>>>(hw, x, gidx, out);
    }
}

// Round 7
// 762.802 us; speedup vs baseline: 1.3401x; 1.1961x over previous
//
#include <hip/hip_runtime.h>
#include <hip/hip_fp16.h>

// RzLinear: C[N,M] = A[N,K] * W[K,M],  W[k,m] = hw[gidx[k*M+m]]
// Round 7 (= round 6 resubmitted; infra timeout, never measured):
//  - numerics: drop Wl plane. 2-term split: (Ah + Al) * Wh. A stays exact
//    (hi/lo f16 pair); W rounded to f16 (adds ~7e-4 absmax, negligible vs
//    the pinned 0.0156 baseline). MFMA/k-step 96->64, prep volume halved.
//  - prep: chunk-starts hoisted to LDS once per block (were re-read 32x).
//  - GEMM structure identical to round 5 (2-barrier, 256x128 block, grid
//    1024, XOR-swizzled LDS, global_load_lds W staging).

#define N_TOK 8192
#define KDIM  4096
#define MDIM  4096

#define PLANE_BYTES (33554432ull)     // f16 plane 4096*4096*2
#define WS_NEEDED   (33554432ull)     // one plane (Wh only)

typedef _Float16 f16x8 __attribute__((ext_vector_type(8)));
typedef _Float16 f16x4 __attribute__((ext_vector_type(4)));
typedef float    f32x4 __attribute__((ext_vector_type(4)));

__device__ __forceinline__ void gload16(const void* g, void* l) {
    __builtin_amdgcn_global_load_lds(
        (const __attribute__((address_space(1))) unsigned int*)g,
        (__attribute__((address_space(3))) unsigned int*)l, 16, 0, 0);
}

// ---------------- kernel 1: Wh materialization ----------------
// Tile ti = mt*128 + kt. Output granule p = r*4 + qphys (16B = 8 k-elems of
// m-row r), qphys = qlog ^ ((r>>1)&3)  [pre-swizzled for GEMM ds_reads].
// Chunk starts (128 per tile) loaded once into LDS, then per-thread:
// 8 LDS-broadcast reads + 8 L2 hw reads + 1 coalesced 16B store.
__global__ __launch_bounds__(256)
void rz_prep_w4(const float* __restrict__ hw, const int* __restrict__ gidx,
                _Float16* __restrict__ wh) {
    __shared__ int s_start[128];        // [kk*4 + mj], kk=0..31, mj=0..3
    const int t  = threadIdx.x;
    const int ti = blockIdx.x;          // 0..4095
    const int mt = ti >> 7;
    const int kt = ti & 127;

    if (t < 128) {
        const int kk = t >> 2;          // k-local chunk row
        const int mj = t & 3;           // m-chunk within 128
        s_start[t] = gidx[(size_t)(kt * 32 + kk) * MDIM + mt * 128 + mj * 32];
    }
    __syncthreads();

    _Float16* whT = wh + (size_t)ti * 4096;
    #pragma unroll
    for (int pass = 0; pass < 2; ++pass) {
        const int r    = (t >> 2) + pass * 64;   // m-local 0..127
        const int qlog = t & 3;
        const int p    = r * 4 + (qlog ^ ((r >> 1) & 3));
        const int mj   = r >> 5;
        const int mo   = r & 31;

        f16x8 hv;
        #pragma unroll
        for (int j = 0; j < 8; ++j) {
            const int kk = qlog * 8 + j;
            const float v = hw[s_start[kk * 4 + mj] + mo];  // contiguous per chunk
            hv[j] = (_Float16)v;
        }
        *reinterpret_cast<f16x8*>(&whT[p * 8]) = hv;        // coalesced 16B/lane
    }
}

// ---------------- kernel 2: 2-term split-f16 GEMM, 256x128 block ----------------
// 4 waves 2x2; wave tile 128(n) x 64(m) = 8x4 16x16x32 frags, acc 128 VGPR.
// Per (mi,ni): acc += Ah*Wh; acc += Al*Wh.
__global__ __launch_bounds__(256, 2)
void rz_gemm4(const float* __restrict__ x,
              const _Float16* __restrict__ wh,
              float* __restrict__ out) {
    __shared__ __align__(16) _Float16 Ah[8192];   // 256 rows x 32 k
    __shared__ __align__(16) _Float16 Al[8192];
    __shared__ __align__(16) _Float16 Bh[4096];   // 128 cols x 32 k

    const int tid  = threadIdx.x;
    const int lane = tid & 63;
    const int wave = tid >> 6;
    const int wr   = wave >> 1;       // n-half: rows wr*128..
    const int wc   = wave & 1;        // m-half: cols wc*64..

    const int bid = blockIdx.x;
    const int swz = (bid & 7) * 128 + (bid >> 3);   // bijective: 1024 % 8 == 0
    const int n0  = (swz >> 5) * 256;               // 32 n-blocks
    const int mt  = (swz & 31);                     // 32 m-tiles
    const int m0  = mt * 128;

    const int l15  = lane & 15;
    const int qsel = lane >> 4;

    int a_off[8], b_off[4];
    #pragma unroll
    for (int mi = 0; mi < 8; ++mi) {
        const int rr = wr * 128 + mi * 16 + l15;
        a_off[mi] = rr * 32 + ((qsel ^ ((rr >> 1) & 3)) * 8);
    }
    #pragma unroll
    for (int ni = 0; ni < 4; ++ni) {
        const int cc = wc * 64 + ni * 16 + l15;
        b_off[ni] = cc * 32 + ((qsel ^ ((cc >> 1) & 3)) * 8);
    }

    const int ar0 = tid >> 2;     // A staging row base (0..63, +64/pass)
    const int aq0 = tid & 3;      // A staging k-granule

    f32x4 acc[8][4];
    #pragma unroll
    for (int i = 0; i < 8; ++i)
        #pragma unroll
        for (int j = 0; j < 4; ++j)
            acc[i][j] = (f32x4)0.0f;

    for (int kt = 0; kt < KDIM / 32; ++kt) {
        // ---- W: 2x global_load_lds dwordx4 (pre-swizzled src, linear dest) ----
        const _Float16* whT = wh + ((size_t)(mt * 128 + kt)) * 4096;
        gload16(whT + tid * 8,        &Bh[tid * 8]);
        gload16(whT + 2048 + tid * 8, &Bh[2048 + tid * 8]);

        // ---- A: reg-stage fp32 -> f16 hi/lo, swizzled ds_write (4 passes) ----
        #pragma unroll
        for (int pass = 0; pass < 4; ++pass) {
            const int r = ar0 + pass * 64;
            const float* src = &x[(size_t)(n0 + r) * KDIM + kt * 32 + aq0 * 8];
            const float4 v0 = *reinterpret_cast<const float4*>(src);
            const float4 v1 = *reinterpret_cast<const float4*>(src + 4);
            const float s[8] = {v0.x, v0.y, v0.z, v0.w, v1.x, v1.y, v1.z, v1.w};
            f16x8 hv, lv;
            #pragma unroll
            for (int j = 0; j < 8; ++j) {
                const _Float16 h = (_Float16)s[j];
                hv[j] = h;
                lv[j] = (_Float16)(s[j] - (float)h);
            }
            const int phys = r * 32 + ((aq0 ^ ((r >> 1) & 3)) * 8);
            *reinterpret_cast<f16x8*>(&Ah[phys]) = hv;
            *reinterpret_cast<f16x8*>(&Al[phys]) = lv;
        }
        __syncthreads();   // drains vmcnt (gload_lds) + lgkmcnt (ds_write)

        // ---- fragments + 64 MFMA ----
        f16x8 fbh[4];
        #pragma unroll
        for (int ni = 0; ni < 4; ++ni)
            fbh[ni] = *reinterpret_cast<const f16x8*>(&Bh[b_off[ni]]);
        #pragma unroll
        for (int mi = 0; mi < 8; ++mi) {
            const f16x8 fah = *reinterpret_cast<const f16x8*>(&Ah[a_off[mi]]);
            const f16x8 fal = *reinterpret_cast<const f16x8*>(&Al[a_off[mi]]);
            #pragma unroll
            for (int ni = 0; ni < 4; ++ni) {
                acc[mi][ni] = __builtin_amdgcn_mfma_f32_16x16x32_f16(fah, fbh[ni], acc[mi][ni], 0, 0, 0);
                acc[mi][ni] = __builtin_amdgcn_mfma_f32_16x16x32_f16(fal, fbh[ni], acc[mi][ni], 0, 0, 0);
            }
        }
        __syncthreads();
    }

    // ---- epilogue: C/D layout col=lane&15, row=(lane>>4)*4+r ----
    #pragma unroll
    for (int mi = 0; mi < 8; ++mi) {
        const int row = n0 + wr * 128 + mi * 16 + (lane >> 4) * 4;
        #pragma unroll
        for (int ni = 0; ni < 4; ++ni) {
            const int col = m0 + wc * 64 + ni * 16 + l15;
            #pragma unroll
            for (int r = 0; r < 4; ++r)
                out[(size_t)(row + r) * MDIM + col] = acc[mi][ni][r];
        }
    }
}

// ---------------- fallback (round-1 kernel, known-correct, 3-term) ----------------
#define BM 128
#define BN 128
#define LDT 40
__global__ __launch_bounds__(256, 2)
void rz_linear_splitf16_fb(const float* __restrict__ hw,
                           const float* __restrict__ x,
                           const int*   __restrict__ gidx,
                           float*       __restrict__ out) {
    __shared__ __align__(16) _Float16 Ah[BM][LDT];
    __shared__ __align__(16) _Float16 Al[BM][LDT];
    __shared__ __align__(16) _Float16 Wh[BN][LDT];
    __shared__ __align__(16) _Float16 Wl[BN][LDT];
    const int tid  = threadIdx.x;
    const int lane = tid & 63;
    const int wave = tid >> 6;
    const int wr   = wave >> 1;
    const int wc   = wave & 1;
    const int bid = blockIdx.x;
    const int swz = (bid & 7) * 256 + (bid >> 3);
    const int n0  = (swz >> 5) * BM;
    const int m0  = (swz & 31) * BN;
    const int a_row = tid >> 3;
    const int a_kc  = tid & 7;
    const int w_m   = tid & 127;
    const int w_kg  = tid >> 7;
    const int l15  = lane & 15;
    const int koff = (lane >> 4) * 8;
    f32x4 acc[4][4];
    #pragma unroll
    for (int i = 0; i < 4; ++i)
        #pragma unroll
        for (int j = 0; j < 4; ++j) acc[i][j] = (f32x4)0.0f;
    for (int k0 = 0; k0 < KDIM; k0 += 32) {
        #pragma unroll
        for (int p = 0; p < 4; ++p) {
            const int n = a_row + p * 32;
            const float4 v = *reinterpret_cast<const float4*>(
                &x[(size_t)(n0 + n) * KDIM + k0 + a_kc * 4]);
            const _Float16 h0 = (_Float16)v.x, h1 = (_Float16)v.y,
                           h2 = (_Float16)v.z, h3 = (_Float16)v.w;
            f16x4 hv = {h0, h1, h2, h3};
            f16x4 lv = {(_Float16)(v.x - (float)h0), (_Float16)(v.y - (float)h1),
                        (_Float16)(v.z - (float)h2), (_Float16)(v.w - (float)h3)};
            *reinterpret_cast<f16x4*>(&Ah[n][a_kc * 4]) = hv;
            *reinterpret_cast<f16x4*>(&Al[n][a_kc * 4]) = lv;
        }
        #pragma unroll
        for (int q = 0; q < 2; ++q) {
            const int kb = (w_kg + 2 * q) * 8;
            float wv[8];
            #pragma unroll
            for (int j = 0; j < 8; ++j) {
                const int k = k0 + kb + j;
                wv[j] = hw[gidx[k * MDIM + m0 + w_m]];
            }
            f16x8 hv, lv;
            #pragma unroll
            for (int j = 0; j < 8; ++j) {
                const _Float16 h = (_Float16)wv[j];
                hv[j] = h;
                lv[j] = (_Float16)(wv[j] - (float)h);
            }
            *reinterpret_cast<f16x8*>(&Wh[w_m][kb]) = hv;
            *reinterpret_cast<f16x8*>(&Wl[w_m][kb]) = lv;
        }
        __syncthreads();
        f16x8 ah[4], al[4], bh[4], bl[4];
        #pragma unroll
        for (int mi = 0; mi < 4; ++mi) {
            const int r = wr * 64 + mi * 16 + l15;
            ah[mi] = *reinterpret_cast<const f16x8*>(&Ah[r][koff]);
            al[mi] = *reinterpret_cast<const f16x8*>(&Al[r][koff]);
        }
        #pragma unroll
        for (int ni = 0; ni < 4; ++ni) {
            const int c = wc * 64 + ni * 16 + l15;
            bh[ni] = *reinterpret_cast<const f16x8*>(&Wh[c][koff]);
            bl[ni] = *reinterpret_cast<const f16x8*>(&Wl[c][koff]);
        }
        #pragma unroll
        for (int mi = 0; mi < 4; ++mi)
            #pragma unroll
            for (int ni = 0; ni < 4; ++ni) {
                acc[mi][ni] = __builtin_amdgcn_mfma_f32_16x16x32_f16(ah[mi], bh[ni], acc[mi][ni], 0, 0, 0);
                acc[mi][ni] = __builtin_amdgcn_mfma_f32_16x16x32_f16(ah[mi], bl[ni], acc[mi][ni], 0, 0, 0);
                acc[mi][ni] = __builtin_amdgcn_mfma_f32_16x16x32_f16(al[mi], bh[ni], acc[mi][ni], 0, 0, 0);
            }
        __syncthreads();
    }
    #pragma unroll
    for (int mi = 0; mi < 4; ++mi) {
        const int row = n0 + wr * 64 + mi * 16 + (lane >> 4) * 4;
        #pragma unroll
        for (int ni = 0; ni < 4; ++ni) {
            const int col = m0 + wc * 64 + ni * 16 + l15;
            #pragma unroll
            for (int r = 0; r < 4; ++r)
                out[(size_t)(row + r) * MDIM + col] = acc[mi][ni][r];
        }
    }
}

extern "C" void kernel_launch(void* const* d_in, const int* in_sizes, int n_in,
                              void* d_out, int out_size, void* d_ws, size_t ws_size,
                              hipStream_t stream) {
    const float* hw   = (const float*)d_in[0];
    const float* x    = (const float*)d_in[1];
    const int*   gidx = (const int*)  d_in[2];
    float* out = (float*)d_out;

    if (ws_size >= WS_NEEDED) {
        _Float16* whp = (_Float16*)d_ws;
        rz_prep_w4<<<4096, 256, 0, stream>>>(hw, gidx, whp);
        rz_gemm4<<<1024, 256, 0, stream>>>(x, whp, out);
    } else {
        rz_linear_splitf16_fb<<<2048, 256, 0, stream>>>(hw, x, gidx, out);
    }
}

// Round 9
// 756.479 us; speedup vs baseline: 1.3513x; 1.0084x over previous
//
#include <hip/hip_runtime.h>
#include <hip/hip_fp16.h>

// RzLinear: C[N,M] = A[N,K] * W[K,M],  W[k,m] = hw[gidx[k*M+m]]
// Round 9 (= round 8 resubmitted; infra timeout, never measured):
//  - gemm5: 64x64 wave tile (acc 64 -> 3 waves/SIMD), 128x128 block, FULL
//    double-buffer (A+B, 48KB) with ONE raw s_barrier per k-step and
//    per-wave counted drains (T4) -- __syncthreads' vmcnt(0) drain was
//    killing all prefetch (round-4 lesson). setprio around MFMA.
//  - prep_w5: dense chunk loads via LDS transpose tile (padded [128][40]),
//    2 threads/chunk x 16 consecutive floats, then granule assembly.
//  Numerics identical to round 7 (2-term (Ah+Al)*Wh, same op order).

#define N_TOK 8192
#define KDIM  4096
#define MDIM  4096

#define WS_NEEDED   (33554432ull)     // one f16 plane (Wh)

typedef _Float16 f16x8 __attribute__((ext_vector_type(8)));
typedef _Float16 f16x4 __attribute__((ext_vector_type(4)));
typedef float    f32x4 __attribute__((ext_vector_type(4)));

__device__ __forceinline__ void gload16(const void* g, void* l) {
    __builtin_amdgcn_global_load_lds(
        (const __attribute__((address_space(1))) unsigned int*)g,
        (__attribute__((address_space(3))) unsigned int*)l, 16, 0, 0);
}

// ---------------- kernel 1: Wh materialization (2-phase LDS) ----------------
// Tile ti = mt*128 + kt. Phys granule p = r*4 + (qlog ^ ((r>>1)&3)) holds
// 8 k-consecutive f16 of m-row r (pre-swizzled for GEMM ds_reads).
// Phase 1: 2 threads/chunk load 16 consecutive floats each (dense, L1-
// amortized), convert, store into padded Th[128][40] (16B-aligned).
// Phase 2: gather 8 rows per granule (~2-way banks), coalesced-ish store.
__global__ __launch_bounds__(256)
void rz_prep_w5(const float* __restrict__ hw, const int* __restrict__ gidx,
                _Float16* __restrict__ wh) {
    __shared__ int s_start[128];                 // [kk*4 + mj]
    __shared__ __align__(16) _Float16 Th[128][40];  // [chunk][m-offset], padded
    const int t  = threadIdx.x;
    const int ti = blockIdx.x;          // 0..4095
    const int mt = ti >> 7;
    const int kt = ti & 127;

    if (t < 128) {
        const int kk = t >> 2;          // k-local chunk row 0..31
        const int mj = t & 3;           // m-chunk 0..3
        s_start[t] = gidx[(size_t)(kt * 32 + kk) * MDIM + mt * 128 + mj * 32];
    }
    __syncthreads();

    // phase 1: chunk c = t>>1, half h = t&1 -> 16 consecutive floats
    {
        const int c = t >> 1;
        const int h = t & 1;
        const int base = s_start[c] + h * 16;
        float v[16];
        #pragma unroll
        for (int i = 0; i < 16; ++i) v[i] = hw[base + i];
        f16x8 g0, g1;
        #pragma unroll
        for (int i = 0; i < 8; ++i) { g0[i] = (_Float16)v[i]; g1[i] = (_Float16)v[8 + i]; }
        *reinterpret_cast<f16x8*>(&Th[c][h * 16])     = g0;
        *reinterpret_cast<f16x8*>(&Th[c][h * 16 + 8]) = g1;
    }
    __syncthreads();

    // phase 2: r = t&127, qpair = t>>7; 2 granules per thread
    {
        const int r     = t & 127;
        const int qpair = t >> 7;
        const int mj    = r >> 5;
        const int mo    = r & 31;
        _Float16* whT = wh + (size_t)ti * 4096;
        #pragma unroll
        for (int qi = 0; qi < 2; ++qi) {
            const int qlog = qpair * 2 + qi;
            f16x8 hv;
            #pragma unroll
            for (int j = 0; j < 8; ++j)
                hv[j] = Th[(qlog * 8 + j) * 4 + mj][mo];
            const int p = r * 4 + (qlog ^ ((r >> 1) & 3));
            *reinterpret_cast<f16x8*>(&whT[p * 8]) = hv;
        }
    }
}

// ---------------- kernel 2: 2-term GEMM, 1-barrier dbuf pipeline ----------------
// 128x128 block, 4 waves 2x2, wave tile 64x64 (4x4 frags, acc 64 AGPR).
__global__ __launch_bounds__(256, 3)
void rz_gemm5(const float* __restrict__ x,
              const _Float16* __restrict__ wh,
              float* __restrict__ out) {
    __shared__ __align__(16) _Float16 Ah[2][4096];   // 128 rows x 32 k
    __shared__ __align__(16) _Float16 Al[2][4096];
    __shared__ __align__(16) _Float16 Bh[2][4096];   // 128 cols x 32 k

    const int tid  = threadIdx.x;
    const int lane = tid & 63;
    const int wave = tid >> 6;
    const int wr   = wave >> 1;
    const int wc   = wave & 1;

    const int bid = blockIdx.x;
    const int swz = (bid & 7) * 256 + (bid >> 3);   // bijective: 2048 % 8 == 0
    const int n0  = (swz >> 5) * 128;               // 64 n-blocks
    const int mt  = (swz & 31);                     // 32 m-tiles
    const int m0  = mt * 128;

    const int l15  = lane & 15;
    const int qsel = lane >> 4;

    int a_off[4], b_off[4];
    #pragma unroll
    for (int mi = 0; mi < 4; ++mi) {
        const int rr = wr * 64 + mi * 16 + l15;
        a_off[mi] = rr * 32 + ((qsel ^ ((rr >> 1) & 3)) * 8);
    }
    #pragma unroll
    for (int ni = 0; ni < 4; ++ni) {
        const int cc = wc * 64 + ni * 16 + l15;
        b_off[ni] = cc * 32 + ((qsel ^ ((cc >> 1) & 3)) * 8);
    }

    const int ar0 = tid >> 2;     // A staging row base (0..63, +64 on pass 1)
    const int aq0 = tid & 3;      // A staging k-granule

    f32x4 acc[4][4];
    #pragma unroll
    for (int i = 0; i < 4; ++i)
        #pragma unroll
        for (int j = 0; j < 4; ++j)
            acc[i][j] = (f32x4)0.0f;

    float4 av[2][2];              // A prefetch registers (16 floats)

    #define LOAD_A(KT) do {                                                   \
        _Pragma("unroll")                                                     \
        for (int pp = 0; pp < 2; ++pp) {                                      \
            const int r = ar0 + pp * 64;                                      \
            const float* src = &x[(size_t)(n0 + r) * KDIM + (KT) * 32 + aq0 * 8]; \
            av[pp][0] = *reinterpret_cast<const float4*>(src);                \
            av[pp][1] = *reinterpret_cast<const float4*>(src + 4);            \
        } } while (0)

    #define WRITE_A(BUF) do {                                                 \
        _Pragma("unroll")                                                     \
        for (int pp = 0; pp < 2; ++pp) {                                      \
            const int r = ar0 + pp * 64;                                      \
            const float s[8] = {av[pp][0].x, av[pp][0].y, av[pp][0].z, av[pp][0].w, \
                                av[pp][1].x, av[pp][1].y, av[pp][1].z, av[pp][1].w}; \
            f16x8 hv, lv;                                                     \
            _Pragma("unroll")                                                 \
            for (int j = 0; j < 8; ++j) {                                     \
                const _Float16 h = (_Float16)s[j];                            \
                hv[j] = h;                                                    \
                lv[j] = (_Float16)(s[j] - (float)h);                          \
            }                                                                 \
            const int phys = r * 32 + ((aq0 ^ ((r >> 1) & 3)) * 8);           \
            *reinterpret_cast<f16x8*>(&Ah[BUF][phys]) = hv;                   \
            *reinterpret_cast<f16x8*>(&Al[BUF][phys]) = lv;                   \
        } } while (0)

    #define STAGE_W(KT, BUF) do {                                             \
        const _Float16* whT = wh + ((size_t)(mt * 128 + (KT))) * 4096;        \
        gload16(whT + tid * 8,        &Bh[BUF][tid * 8]);                     \
        gload16(whT + 2048 + tid * 8, &Bh[BUF][2048 + tid * 8]);              \
    } while (0)

    // ---- prologue: stage tile 0 into buf 0 ----
    LOAD_A(0);
    STAGE_W(0, 0);
    WRITE_A(0);
    __syncthreads();   // full drain once

    for (int t = 0; t < 128; ++t) {
        const int cur  = t & 1;
        const int nxt  = cur ^ 1;
        const bool more = (t < 127);

        if (more) {
            LOAD_A(t + 1);          // global->reg, in flight across MFMA
            STAGE_W(t + 1, nxt);    // global->LDS (other buffer)
        }

        // fragment reads of current tile (compiler inserts counted lgkmcnt)
        f16x8 fah[4], fal[4], fbh[4];
        #pragma unroll
        for (int mi = 0; mi < 4; ++mi) {
            fah[mi] = *reinterpret_cast<const f16x8*>(&Ah[cur][a_off[mi]]);
            fal[mi] = *reinterpret_cast<const f16x8*>(&Al[cur][a_off[mi]]);
        }
        #pragma unroll
        for (int ni = 0; ni < 4; ++ni)
            fbh[ni] = *reinterpret_cast<const f16x8*>(&Bh[cur][b_off[ni]]);

        if (more) WRITE_A(nxt);     // convert+ds_write next A; no cross-wave
                                    // hazard (writes nxt, reads cur)

        __builtin_amdgcn_s_setprio(1);
        #pragma unroll
        for (int mi = 0; mi < 4; ++mi)
            #pragma unroll
            for (int ni = 0; ni < 4; ++ni) {
                acc[mi][ni] = __builtin_amdgcn_mfma_f32_16x16x32_f16(fah[mi], fbh[ni], acc[mi][ni], 0, 0, 0);
                acc[mi][ni] = __builtin_amdgcn_mfma_f32_16x16x32_f16(fal[mi], fbh[ni], acc[mi][ni], 0, 0, 0);
            }
        __builtin_amdgcn_s_setprio(0);

        if (more) {
            // per-wave drains: W gloads + A ds_writes done; then barrier.
            asm volatile("s_waitcnt vmcnt(0) lgkmcnt(0)" ::: "memory");
            __builtin_amdgcn_sched_barrier(0);
            __builtin_amdgcn_s_barrier();
        }
    }

    // ---- epilogue: C/D layout col=lane&15, row=(lane>>4)*4+r ----
    #pragma unroll
    for (int mi = 0; mi < 4; ++mi) {
        const int row = n0 + wr * 64 + mi * 16 + (lane >> 4) * 4;
        #pragma unroll
        for (int ni = 0; ni < 4; ++ni) {
            const int col = m0 + wc * 64 + ni * 16 + l15;
            #pragma unroll
            for (int r = 0; r < 4; ++r)
                out[(size_t)(row + r) * MDIM + col] = acc[mi][ni][r];
        }
    }
    #undef LOAD_A
    #undef WRITE_A
    #undef STAGE_W
}

// ---------------- fallback (round-1 kernel, known-correct, 3-term) ----------------
#define BM 128
#define BN 128
#define LDT 40
__global__ __launch_bounds__(256, 2)
void rz_linear_splitf16_fb(const float* __restrict__ hw,
                           const float* __restrict__ x,
                           const int*   __restrict__ gidx,
                           float*       __restrict__ out) {
    __shared__ __align__(16) _Float16 Ah[BM][LDT];
    __shared__ __align__(16) _Float16 Al[BM][LDT];
    __shared__ __align__(16) _Float16 Wh[BN][LDT];
    __shared__ __align__(16) _Float16 Wl[BN][LDT];
    const int tid  = threadIdx.x;
    const int lane = tid & 63;
    const int wave = tid >> 6;
    const int wr   = wave >> 1;
    const int wc   = wave & 1;
    const int bid = blockIdx.x;
    const int swz = (bid & 7) * 256 + (bid >> 3);
    const int n0  = (swz >> 5) * BM;
    const int m0  = (swz & 31) * BN;
    const int a_row = tid >> 3;
    const int a_kc  = tid & 7;
    const int w_m   = tid & 127;
    const int w_kg  = tid >> 7;
    const int l15  = lane & 15;
    const int koff = (lane >> 4) * 8;
    f32x4 acc[4][4];
    #pragma unroll
    for (int i = 0; i < 4; ++i)
        #pragma unroll
        for (int j = 0; j < 4; ++j) acc[i][j] = (f32x4)0.0f;
    for (int k0 = 0; k0 < KDIM; k0 += 32) {
        #pragma unroll
        for (int p = 0; p < 4; ++p) {
            const int n = a_row + p * 32;
            const float4 v = *reinterpret_cast<const float4*>(
                &x[(size_t)(n0 + n) * KDIM + k0 + a_kc * 4]);
            const _Float16 h0 = (_Float16)v.x, h1 = (_Float16)v.y,
                           h2 = (_Float16)v.z, h3 = (_Float16)v.w;
            f16x4 hv = {h0, h1, h2, h3};
            f16x4 lv = {(_Float16)(v.x - (float)h0), (_Float16)(v.y - (float)h1),
                        (_Float16)(v.z - (float)h2), (_Float16)(v.w - (float)h3)};
            *reinterpret_cast<f16x4*>(&Ah[n][a_kc * 4]) = hv;
            *reinterpret_cast<f16x4*>(&Al[n][a_kc * 4]) = lv;
        }
        #pragma unroll
        for (int q = 0; q < 2; ++q) {
            const int kb = (w_kg + 2 * q) * 8;
            float wv[8];
            #pragma unroll
            for (int j = 0; j < 8; ++j) {
                const int k = k0 + kb + j;
                wv[j] = hw[gidx[k * MDIM + m0 + w_m]];
            }
            f16x8 hv, lv;
            #pragma unroll
            for (int j = 0; j < 8; ++j) {
                const _Float16 h = (_Float16)wv[j];
                hv[j] = h;
                lv[j] = (_Float16)(wv[j] - (float)h);
            }
            *reinterpret_cast<f16x8*>(&Wh[w_m][kb]) = hv;
            *reinterpret_cast<f16x8*>(&Wl[w_m][kb]) = lv;
        }
        __syncthreads();
        f16x8 ah[4], al[4], bh[4], bl[4];
        #pragma unroll
        for (int mi = 0; mi < 4; ++mi) {
            const int r = wr * 64 + mi * 16 + l15;
            ah[mi] = *reinterpret_cast<const f16x8*>(&Ah[r][koff]);
            al[mi] = *reinterpret_cast<const f16x8*>(&Al[r][koff]);
        }
        #pragma unroll
        for (int ni = 0; ni < 4; ++ni) {
            const int c = wc * 64 + ni * 16 + l15;
            bh[ni] = *reinterpret_cast<const f16x8*>(&Wh[c][koff]);
            bl[ni] = *reinterpret_cast<const f16x8*>(&Wl[c][koff]);
        }
        #pragma unroll
        for (int mi = 0; mi < 4; ++mi)
            #pragma unroll
            for (int ni = 0; ni < 4; ++ni) {
                acc[mi][ni] = __builtin_amdgcn_mfma_f32_16x16x32_f16(ah[mi], bh[ni], acc[mi][ni], 0, 0, 0);
                acc[mi][ni] = __builtin_amdgcn_mfma_f32_16x16x32_f16(ah[mi], bl[ni], acc[mi][ni], 0, 0, 0);
                acc[mi][ni] = __builtin_amdgcn_mfma_f32_16x16x32_f16(al[mi], bh[ni], acc[mi][ni], 0, 0, 0);
            }
        __syncthreads();
    }
    #pragma unroll
    for (int mi = 0; mi < 4; ++mi) {
        const int row = n0 + wr * 64 + mi * 16 + (lane >> 4) * 4;
        #pragma unroll
        for (int ni = 0; ni < 4; ++ni) {
            const int col = m0 + wc * 64 + ni * 16 + l15;
            #pragma unroll
            for (int r = 0; r < 4; ++r)
                out[(size_t)(row + r) * MDIM + col] = acc[mi][ni][r];
        }
    }
}

extern "C" void kernel_launch(void* const* d_in, const int* in_sizes, int n_in,
                              void* d_out, int out_size, void* d_ws, size_t ws_size,
                              hipStream_t stream) {
    const float* hw   = (const float*)d_in[0];
    const float* x    = (const float*)d_in[1];
    const int*   gidx = (const int*)  d_in[2];
    float* out = (float*)d_out;

    if (ws_size >= WS_NEEDED) {
        _Float16* whp = (_Float16*)d_ws;
        rz_prep_w5<<<4096, 256, 0, stream>>>(hw, gidx, whp);
        rz_gemm5<<<2048, 256, 0, stream>>>(x, whp, out);
    } else {
        rz_linear_splitf16_fb<<<2048, 256, 0, stream>>>(hw, x, gidx, out);
    }
}